// Round 1
// baseline (484.430 us; speedup 1.0000x reference)
//
#include <hip/hip_runtime.h>
#include <hip/hip_bf16.h>
#include <math.h>

// VectorField: out = ((silu(silu(silu([x|enc]@W0)@W1)@W2))@W3 + b3
// enc = 16-level hash-grid trilinear encode of (cond0, cond1, t).
// Strategy: f16 activations/weights, fp32-accum MFMA (16x16x32_f16),
// m97-style 128x128xBK32 GEMM with global_load_lds staging.

#define B_ROWS 65536
#define T_SIZE 524288   // 2^19
#define T_MASK (T_SIZE - 1)

typedef _Float16 f16;
typedef _Float16 f16x8 __attribute__((ext_vector_type(8)));
typedef _Float16 f16x4 __attribute__((ext_vector_type(4)));
typedef float f32x4 __attribute__((ext_vector_type(4)));

struct Scales { float s[16]; };

#define GLD16(gsrc, ldst) __builtin_amdgcn_global_load_lds( \
    (const __attribute__((address_space(1))) void*)(gsrc),  \
    (__attribute__((address_space(3))) void*)(ldst), 16, 0, 0)

// ---------------- prep kernels ----------------

// dst[n][k] = (f16) src[k][n]   (weights: [K,N] fp32 -> [N,K] f16)
__global__ void transpose_w(const float* __restrict__ src, f16* __restrict__ dst,
                            int K, int N) {
  int tid = blockIdx.x * blockDim.x + threadIdx.x;
  if (tid >= K * N) return;
  int n = tid / K, k = tid - n * K;
  dst[tid] = (f16)src[(size_t)k * N + n];
}

// x [B,768] fp32 -> h0[b, 0:768] f16 (row pitch 832)
__global__ void prep_x(const float* __restrict__ x, f16* __restrict__ h0) {
  int tid = blockIdx.x * blockDim.x + threadIdx.x;   // B*192 threads
  int row = tid / 192, c4 = (tid - row * 192) * 4;
  float4 v = *(const float4*)(x + (size_t)row * 768 + c4);
  f16x4 o = { (f16)v.x, (f16)v.y, (f16)v.z, (f16)v.w };
  *(f16x4*)(h0 + (size_t)row * 832 + c4) = o;
}

// hash encode: thread per (row, level). h0[b, 768 + 4l .. +4) = enc
__global__ void hash_enc(const float* __restrict__ t, const float* __restrict__ cond,
                         const float* __restrict__ tables, f16* __restrict__ h0,
                         Scales sc) {
  int tid = blockIdx.x * blockDim.x + threadIdx.x;   // B*16 threads
  int b = tid >> 4, l = tid & 15;
  float c0 = cond[2 * b], c1 = cond[2 * b + 1], c2 = t[b];
  float s = sc.s[l];
  float xf0 = c0 * s, xf1 = c1 * s, xf2 = c2 * s;
  float xl0 = floorf(xf0), xl1 = floorf(xf1), xl2 = floorf(xf2);
  float w0 = xf0 - xl0, w1 = xf1 - xl1, w2 = xf2 - xl2;
  unsigned xi0 = (unsigned)xl0, xi1 = (unsigned)xl1, xi2 = (unsigned)xl2;

  const float4* tl = (const float4*)tables + (size_t)l * T_SIZE;
  float a0 = 0.f, a1 = 0.f, a2 = 0.f, a3 = 0.f;
#pragma unroll
  for (int c = 0; c < 8; ++c) {
    unsigned ax = (c >> 2) & 1u, ay = (c >> 1) & 1u, az = c & 1u;
    unsigned hh = (xi0 + ax) ^ ((xi1 + ay) * 2654435761u) ^ ((xi2 + az) * 805459861u);
    float4 f = tl[hh & T_MASK];
    float wcw = (ax ? w0 : 1.f - w0) * (ay ? w1 : 1.f - w1) * (az ? w2 : 1.f - w2);
    a0 += wcw * f.x; a1 += wcw * f.y; a2 += wcw * f.z; a3 += wcw * f.w;
  }
  f16x4 o = { (f16)a0, (f16)a1, (f16)a2, (f16)a3 };
  *(f16x4*)(h0 + (size_t)b * 832 + 768 + l * 4) = o;
}

// ---------------- GEMM ----------------
// C[M,N] = act(A[M,K] @ Wt[N,K]^T + bias). 128x128 tile, BK=32, 4 waves (2x2),
// each wave 64x64 via 4x4 frags of v_mfma_f32_16x16x32_f16.
template<int K, int N, bool SILU, bool OUTF32>
__global__ __launch_bounds__(256, 2) void gemm_f16(
    const f16* __restrict__ A, const f16* __restrict__ Wt,
    const float* __restrict__ bias, f16* __restrict__ Of16,
    float* __restrict__ Of32) {
  __shared__ f16 As[128 * 32];
  __shared__ f16 Bs[128 * 32];
  const int tid = threadIdx.x;
  const int wave = tid >> 6;
  const int lane = tid & 63;
  const int l16 = lane & 15, lhi = lane >> 4;
  const int wr = wave >> 1, wc = wave & 1;
  const int colBase = blockIdx.x * 128;   // x = col tile: A-tile L3 reuse
  const int rowBase = blockIdx.y * 128;

  f32x4 acc[4][4] = {};

  // staging: thread t loads 16B: row = t>>2 (0..63), col8 = (t&3)*8
  const int sRow = tid >> 2;
  const int sCol = (tid & 3) * 8;
  const f16* aSrc = A + (size_t)(rowBase + sRow) * K + sCol;
  const f16* bSrc = Wt + (size_t)(colBase + sRow) * K + sCol;
  char* asW = (char*)As + wave * 1024;   // wave-uniform LDS base
  char* bsW = (char*)Bs + wave * 1024;

  for (int k0 = 0; k0 < K; k0 += 32) {
    GLD16(aSrc + k0,                 asW);
    GLD16(aSrc + (size_t)64 * K + k0, asW + 4096);
    GLD16(bSrc + k0,                 bsW);
    GLD16(bSrc + (size_t)64 * K + k0, bsW + 4096);
    __syncthreads();

    f16x8 af[4], bf[4];
#pragma unroll
    for (int mi = 0; mi < 4; ++mi)
      af[mi] = *(const f16x8*)((const char*)As + (wr * 64 + mi * 16 + l16) * 64 + lhi * 16);
#pragma unroll
    for (int ni = 0; ni < 4; ++ni)
      bf[ni] = *(const f16x8*)((const char*)Bs + (wc * 64 + ni * 16 + l16) * 64 + lhi * 16);
#pragma unroll
    for (int mi = 0; mi < 4; ++mi)
#pragma unroll
      for (int ni = 0; ni < 4; ++ni)
        acc[mi][ni] = __builtin_amdgcn_mfma_f32_16x16x32_f16(af[mi], bf[ni], acc[mi][ni], 0, 0, 0);
    __syncthreads();
  }

  // epilogue: C/D frag layout col=lane&15, row=(lane>>4)*4+r (m89-verified)
#pragma unroll
  for (int ni = 0; ni < 4; ++ni) {
    const int col = colBase + wc * 64 + ni * 16 + l16;
    const float bv = bias[col];
#pragma unroll
    for (int mi = 0; mi < 4; ++mi) {
#pragma unroll
      for (int r = 0; r < 4; ++r) {
        const int row = rowBase + wr * 64 + mi * 16 + lhi * 4 + r;
        float v = acc[mi][ni][r] + bv;
        if (SILU) v = v / (1.f + __expf(-v));
        if (OUTF32) Of32[(size_t)row * N + col] = v;
        else        Of16[(size_t)row * N + col] = (f16)v;
      }
    }
  }
}

// ---------------- launch ----------------

extern "C" void kernel_launch(void* const* d_in, const int* in_sizes, int n_in,
                              void* d_out, int out_size, void* d_ws, size_t ws_size,
                              hipStream_t stream) {
  const float* t    = (const float*)d_in[0];
  const float* x    = (const float*)d_in[1];
  const float* cond = (const float*)d_in[2];
  const float* tab  = (const float*)d_in[3];
  const float* W0   = (const float*)d_in[4];
  const float* b0   = (const float*)d_in[5];
  const float* W1   = (const float*)d_in[6];
  const float* b1   = (const float*)d_in[7];
  const float* W2   = (const float*)d_in[8];
  const float* b2   = (const float*)d_in[9];
  const float* W3   = (const float*)d_in[10];
  const float* b3   = (const float*)d_in[11];
  float* out = (float*)d_out;

  // ws layout (bytes); all 16B-aligned
  char* ws = (char*)d_ws;
  f16* Wt0 = (f16*)(ws + 0);            // 832*512*2 = 851968
  f16* Wt1 = (f16*)(ws + 851968);       // 512*512*2 = 524288
  f16* Wt2 = (f16*)(ws + 1376256);      // 524288
  f16* Wt3 = (f16*)(ws + 1900544);      // 768*512*2 = 786432
  f16* H0  = (f16*)(ws + 2686976);      // 65536*832*2 = 109051904
  f16* H1  = (f16*)(ws + 111738880);    // 65536*512*2 = 67108864
  f16* H2  = (f16*)(ws + 178847744);    // 67108864 ; end = 245956608
  (void)in_sizes; (void)n_in; (void)out_size; (void)ws_size;

  // weight transpose + f16 convert
  transpose_w<<<dim3(1664), 256, 0, stream>>>(W0, Wt0, 832, 512);
  transpose_w<<<dim3(1024), 256, 0, stream>>>(W1, Wt1, 512, 512);
  transpose_w<<<dim3(1024), 256, 0, stream>>>(W2, Wt2, 512, 512);
  transpose_w<<<dim3(1536), 256, 0, stream>>>(W3, Wt3, 512, 768);

  // h0 = [x | enc] in f16
  prep_x<<<dim3(49152), 256, 0, stream>>>(x, H0);

  Scales sc;
  {
    double growth = exp((log(512.0) - log(16.0)) / 15.0);
    for (int l = 0; l < 16; ++l) sc.s[l] = (float)floor(16.0 * pow(growth, (double)l));
  }
  hash_enc<<<dim3(4096), 256, 0, stream>>>(t, cond, tab, H0, sc);

  // MLP chain
  gemm_f16<832, 512, true,  false><<<dim3(4, 512), 256, 0, stream>>>(H0, Wt0, b0, H1, nullptr);
  gemm_f16<512, 512, true,  false><<<dim3(4, 512), 256, 0, stream>>>(H1, Wt1, b1, H2, nullptr);
  gemm_f16<512, 512, true,  false><<<dim3(4, 512), 256, 0, stream>>>(H2, Wt2, b2, H1, nullptr);
  gemm_f16<512, 768, false, true ><<<dim3(6, 512), 256, 0, stream>>>(H1, Wt3, b3, nullptr, out);
}